// Round 9
// baseline (37.537 us; speedup 1.0000x reference)
//
#include <hip/hip_runtime.h>

#define IMG_H 512
#define IMG_W 512
#define NB    32
#define HW    (IMG_H * IMG_W)
#define SEGS  32             // 16-px segments per row
#define RPB   8              // rows per block (256 threads / 32 segs)
#define GX    (IMG_H / RPB)  // 64 blocks in x per batch
// d_ws layout (u64 units): [0] global batch-done counter; [16 + b*16] batch b's
// packed accumulator (inter bits 0-19, uni bits 20-39, done-count bits 40-47),
// each on its own 128B cacheline.

// Packed class masks for 16 px: bits 0..15 = (y==1), bits 16..31 = (y==2).
// y in {0,1,2}  =>  (y==1) == (y&1), (y==2) == (y>>1). No compares needed.
__device__ __forceinline__ unsigned build16(const int* __restrict__ row) {
    unsigned m = 0u;
    #pragma unroll
    for (int q = 0; q < 4; ++q) {
        const int4 w = *reinterpret_cast<const int4*>(row + 4 * q);
        const unsigned b1 = (unsigned)(w.x & 1)        | ((unsigned)(w.y & 1) << 1)
                          | ((unsigned)(w.z & 1) << 2) | ((unsigned)(w.w & 1) << 3);
        const unsigned b2 = (unsigned)(w.x >> 1)        | ((unsigned)(w.y >> 1) << 1)
                          | ((unsigned)(w.z >> 1) << 2) | ((unsigned)(w.w >> 1) << 3);
        m |= (b1 << (4 * q)) | (b2 << (16 + 4 * q));
    }
    return m;
}

// R5 body: thread = 16-px row segment; wave = 2 adjacent rows x 32 segs.
// Epilogue: one packed u64 atomic per block; batch-last block bumps global ctr;
// final block's wave 0 computes the mean of per-batch ratios and writes out.
__global__ __launch_bounds__(256) void iou_kernel(const float* __restrict__ yhat,
                                                  const int* __restrict__ y,
                                                  unsigned long long* __restrict__ ws,
                                                  float* __restrict__ out) {
    const int b   = blockIdx.y;
    const int t   = blockIdx.x * 256 + threadIdx.x;
    const int h   = t >> 5;                 // row
    const int seg = t & 31;
    const int wbase = seg << 4;             // *16

    const int lane     = threadIdx.x & 63;
    const bool lowHalf = (lane < 32);

    // ---- y masks first (consumed first), then the dominant yhat stream ----
    const int* yb = y + (size_t)b * HW;
    const int ho  = lowHalf ? (h - 1) : (h + 1);            // outward row
    const bool ov = (unsigned)ho < IMG_H;
    const int hoc = ov ? ho : h;

    const unsigned mOwn = build16(yb + (size_t)h   * IMG_W + wbase);
    const unsigned mOut = build16(yb + (size_t)hoc * IMG_W + wbase);

    const float* yh = yhat + (size_t)b * 3 * HW + (size_t)h * IMG_W + wbase;
    const float4 qa0 = *reinterpret_cast<const float4*>(yh);
    const float4 qa1 = *reinterpret_cast<const float4*>(yh + 4);
    const float4 qa2 = *reinterpret_cast<const float4*>(yh + 8);
    const float4 qa3 = *reinterpret_cast<const float4*>(yh + 12);
    const float4 qb0 = *reinterpret_cast<const float4*>(yh + HW);
    const float4 qb1 = *reinterpret_cast<const float4*>(yh + HW + 4);
    const float4 qb2 = *reinterpret_cast<const float4*>(yh + HW + 8);
    const float4 qb3 = *reinterpret_cast<const float4*>(yh + HW + 12);
    const float4 qc0 = *reinterpret_cast<const float4*>(yh + 2 * HW);
    const float4 qc1 = *reinterpret_cast<const float4*>(yh + 2 * HW + 4);
    const float4 qc2 = *reinterpret_cast<const float4*>(yh + 2 * HW + 8);
    const float4 qc3 = *reinterpret_cast<const float4*>(yh + 2 * HW + 12);

    // ---- Assemble 3 rows via partner shuffle; L/R halo shuffles ----
    const unsigned mPar = __shfl(mOwn, lane ^ 32, 64);      // partner row
    const unsigned mT = lowHalf ? mOut : mPar;
    const unsigned mB = lowHalf ? mPar : mOut;
    const bool vT = lowHalf ? ov : true;
    const bool vB = lowHalf ? true : ov;

    const int laneL = (lane + 63) & 63;   // cross-half leakage only at seg borders (masked)
    const int laneR = (lane + 1) & 63;
    const unsigned tL = __shfl(mT, laneL, 64),   tR = __shfl(mT, laneR, 64);
    const unsigned cL = __shfl(mOwn, laneL, 64), cR = __shfl(mOwn, laneR, 64);
    const unsigned bL = __shfl(mB, laneL, 64),   bR = __shfl(mB, laneR, 64);

    // ext bit j = column wbase-1+j (j=0..17)
    #define EXT1(m, ml, mr) ((((m) & 0xFFFFu) << 1) | (((ml) >> 15) & 1u) | (((mr) & 1u) << 17))
    #define EXT2(m, ml, mr) ((((m) >> 16) << 1)     | ((ml) >> 31)        | ((((mr) >> 16) & 1u) << 17))
    const unsigned eT1 = EXT1(mT, tL, tR),   eT2 = EXT2(mT, tL, tR);
    const unsigned eC1 = EXT1(mOwn, cL, cR), eC2 = EXT2(mOwn, cL, cR);
    const unsigned eB1 = EXT1(mB, bL, bR),   eB2 = EXT2(mB, bL, bR);

    const unsigned ALL = 0x3FFFFu;
    unsigned vmask = ALL;
    if (seg == 0)        vmask &= ~1u;
    if (seg == SEGS - 1) vmask &= ~(1u << 17);
    const unsigned inv = ALL & ~vmask;

    unsigned and1 = eC1 & (vT ? eT1 : ALL) & (vB ? eB1 : ALL);
    unsigned and2 = eC2 & (vT ? eT2 : ALL) & (vB ? eB2 : ALL);
    unsigned or1  = eC1 | (vT ? eT1 : 0u)  | (vB ? eB1 : 0u);
    unsigned or2  = eC2 | (vT ? eT2 : 0u)  | (vB ? eB2 : 0u);
    and1 |= inv;   and2 |= inv;
    or1  &= vmask; or2  &= vmask;

    const unsigned E1 = and1 & (and1 >> 1) & (and1 >> 2);
    const unsigned E2 = and2 & (and2 >> 1) & (and2 >> 2);
    const unsigned D1 = or1  | (or1  >> 1) | (or1  >> 2);
    const unsigned D2 = or2  | (or2  >> 1) | (or2  >> 2);

    // ---- Argmax -> class bitmasks (strict > = first-occurrence tie-break) ----
    const float A[16]  = {qa0.x,qa0.y,qa0.z,qa0.w, qa1.x,qa1.y,qa1.z,qa1.w,
                          qa2.x,qa2.y,qa2.z,qa2.w, qa3.x,qa3.y,qa3.z,qa3.w};
    const float Bv[16] = {qb0.x,qb0.y,qb0.z,qb0.w, qb1.x,qb1.y,qb1.z,qb1.w,
                          qb2.x,qb2.y,qb2.z,qb2.w, qb3.x,qb3.y,qb3.z,qb3.w};
    const float Cv[16] = {qc0.x,qc0.y,qc0.z,qc0.w, qc1.x,qc1.y,qc1.z,qc1.w,
                          qc2.x,qc2.y,qc2.z,qc2.w, qc3.x,qc3.y,qc3.z,qc3.w};
    unsigned P1 = 0u, P2 = 0u;
    #pragma unroll
    for (int j = 0; j < 16; ++j) {
        int   p    = 0;
        float best = A[j];
        if (Bv[j] > best) { best = Bv[j]; p = 1; }
        if (Cv[j] > best) {               p = 2; }
        P1 |= ((p == 1) ? 1u : 0u) << j;
        P2 |= ((p == 2) ? 1u : 0u) << j;
    }

    const unsigned inter = (unsigned)__popc((D2 & P2) | (D1 & ~D2 & P1));
    const unsigned uni   = (unsigned)__popc((E1 | E2 | P1 | P2) & 0xFFFFu);

    // ---- Reduce: wave -> block ----
    unsigned long long packed = (unsigned long long)inter | ((unsigned long long)uni << 32);
    #pragma unroll
    for (int off = 32; off > 0; off >>= 1)
        packed += __shfl_down(packed, off, 64);

    __shared__ unsigned long long wsum[4];
    const int wave = threadIdx.x >> 6;
    if ((threadIdx.x & 63) == 0) wsum[wave] = packed;
    __syncthreads();

    // ---- One packed atomic per block; done-count rides in the same add ----
    int isFin = 0;
    if (threadIdx.x == 0) {
        const unsigned long long s  = wsum[0] + wsum[1] + wsum[2] + wsum[3];
        const unsigned long long bi = s & 0xFFFFFFFFull;          // block inter (<=4096)
        const unsigned long long bu = s >> 32;                    // block uni   (<=4096)
        const unsigned long long add = bi | (bu << 20) | (1ull << 40);
        const unsigned long long old = atomicAdd(&ws[16 + (size_t)b * 16], add);
        if (((old >> 40) & 0xFFull) == (unsigned long long)(GX - 1)) {  // batch-last block
            __threadfence();
            const unsigned long long o2 = atomicAdd(&ws[0], 1ull);
            isFin = (o2 == (unsigned long long)(NB - 1)) ? 1 : 0;       // final batch done
        }
    }
    const int fin = __shfl(isFin, 0, 64);   // wave 0 sees thread 0's flag; other waves 0

    // ---- Final block, wave 0: 32 parallel line reads -> mean of ratios ----
    if (fin) {
        __threadfence();
        float r = 0.0f;
        if (lane < NB) {
            const unsigned long long p = atomicAdd(&ws[16 + (size_t)lane * 16], 0ull);
            const float fi = (float)(unsigned)(p & 0xFFFFFull);
            const float fu = (float)(unsigned)((p >> 20) & 0xFFFFFull);
            r = fi / fu;
        }
        #pragma unroll
        for (int off = 16; off > 0; off >>= 1)
            r += __shfl_down(r, off, 32);
        if (lane == 0) out[0] = r / (float)NB;
    }
}

extern "C" void kernel_launch(void* const* d_in, const int* in_sizes, int n_in,
                              void* d_out, int out_size, void* d_ws, size_t ws_size,
                              hipStream_t stream) {
    const float* yhat = (const float*)d_in[0];
    const int*   y    = (const int*)d_in[1];
    float*       out  = (float*)d_out;
    unsigned long long* ws = (unsigned long long*)d_ws;

    // Zero ctr line + 32 padded batch lines: (16 + 32*16) u64 = 4224 bytes.
    hipMemsetAsync(d_ws, 0, (16 + NB * 16) * sizeof(unsigned long long), stream);

    dim3 grid(GX, NB, 1);
    iou_kernel<<<grid, 256, 0, stream>>>(yhat, y, ws, out);
}

// Round 10
// 28.009 us; speedup vs baseline: 1.3402x; 1.3402x over previous
//
#include <hip/hip_runtime.h>

#define IMG_H 512
#define IMG_W 512
#define NB    32
#define HW    (IMG_H * IMG_W)
#define SEGS  32             // 16-px segments per row
#define RPB   8              // rows per block (256 threads / 32 segs)
#define GX    (IMG_H / RPB)  // 64 blocks in x
#define NPART GX             // partials per batch

// Packed class masks for 16 px: bits 0..15 = (y==1), bits 16..31 = (y==2).
// y in {0,1,2}  =>  (y==1) == (y&1), (y==2) == (y>>1).
__device__ __forceinline__ unsigned build16(const int* __restrict__ row) {
    unsigned m = 0u;
    #pragma unroll
    for (int q = 0; q < 4; ++q) {
        const int4 w = *reinterpret_cast<const int4*>(row + 4 * q);
        const unsigned b1 = (unsigned)(w.x & 1)        | ((unsigned)(w.y & 1) << 1)
                          | ((unsigned)(w.z & 1) << 2) | ((unsigned)(w.w & 1) << 3);
        const unsigned b2 = (unsigned)(w.x >> 1)        | ((unsigned)(w.y >> 1) << 1)
                          | ((unsigned)(w.z >> 1) << 2) | ((unsigned)(w.w >> 1) << 3);
        m |= (b1 << (4 * q)) | (b2 << (16 + 4 * q));
    }
    return m;
}

// Thread = 16-px row segment; wave = 2 adjacent rows x 32 segs.
// __launch_bounds__(256, 4): min 4 waves/EU -> VGPR cap 128, letting the
// scheduler keep all 20 vector loads in flight (VGPR=32 squeeze was the
// R3-R8 plateau cause).
__global__ __launch_bounds__(256, 4) void iou_kernel(const float* __restrict__ yhat,
                                                     const int* __restrict__ y,
                                                     unsigned long long* __restrict__ part) {
    const int b   = blockIdx.y;
    const int t   = blockIdx.x * 256 + threadIdx.x;
    const int h   = t >> 5;                 // row
    const int seg = t & 31;
    const int wbase = seg << 4;             // *16

    const int lane     = threadIdx.x & 63;
    const bool lowHalf = (lane < 32);

    // ---- y masks first (consumed first), then the dominant yhat stream ----
    const int* yb = y + (size_t)b * HW;
    const int ho  = lowHalf ? (h - 1) : (h + 1);            // outward row
    const bool ov = (unsigned)ho < IMG_H;
    const int hoc = ov ? ho : h;

    const unsigned mOwn = build16(yb + (size_t)h   * IMG_W + wbase);
    const unsigned mOut = build16(yb + (size_t)hoc * IMG_W + wbase);

    const float* yh = yhat + (size_t)b * 3 * HW + (size_t)h * IMG_W + wbase;
    const float4 qa0 = *reinterpret_cast<const float4*>(yh);
    const float4 qa1 = *reinterpret_cast<const float4*>(yh + 4);
    const float4 qa2 = *reinterpret_cast<const float4*>(yh + 8);
    const float4 qa3 = *reinterpret_cast<const float4*>(yh + 12);
    const float4 qb0 = *reinterpret_cast<const float4*>(yh + HW);
    const float4 qb1 = *reinterpret_cast<const float4*>(yh + HW + 4);
    const float4 qb2 = *reinterpret_cast<const float4*>(yh + HW + 8);
    const float4 qb3 = *reinterpret_cast<const float4*>(yh + HW + 12);
    const float4 qc0 = *reinterpret_cast<const float4*>(yh + 2 * HW);
    const float4 qc1 = *reinterpret_cast<const float4*>(yh + 2 * HW + 4);
    const float4 qc2 = *reinterpret_cast<const float4*>(yh + 2 * HW + 8);
    const float4 qc3 = *reinterpret_cast<const float4*>(yh + 2 * HW + 12);

    // ---- Assemble 3 rows via partner shuffle; L/R halo shuffles ----
    const unsigned mPar = __shfl(mOwn, lane ^ 32, 64);      // partner row
    const unsigned mT = lowHalf ? mOut : mPar;
    const unsigned mB = lowHalf ? mPar : mOut;
    const bool vT = lowHalf ? ov : true;
    const bool vB = lowHalf ? true : ov;

    const int laneL = (lane + 63) & 63;   // cross-half leakage only at seg borders (masked)
    const int laneR = (lane + 1) & 63;
    const unsigned tL = __shfl(mT, laneL, 64),   tR = __shfl(mT, laneR, 64);
    const unsigned cL = __shfl(mOwn, laneL, 64), cR = __shfl(mOwn, laneR, 64);
    const unsigned bL = __shfl(mB, laneL, 64),   bR = __shfl(mB, laneR, 64);

    // ext bit j = column wbase-1+j (j=0..17)
    #define EXT1(m, ml, mr) ((((m) & 0xFFFFu) << 1) | (((ml) >> 15) & 1u) | (((mr) & 1u) << 17))
    #define EXT2(m, ml, mr) ((((m) >> 16) << 1)     | ((ml) >> 31)        | ((((mr) >> 16) & 1u) << 17))
    const unsigned eT1 = EXT1(mT, tL, tR),   eT2 = EXT2(mT, tL, tR);
    const unsigned eC1 = EXT1(mOwn, cL, cR), eC2 = EXT2(mOwn, cL, cR);
    const unsigned eB1 = EXT1(mB, bL, bR),   eB2 = EXT2(mB, bL, bR);

    const unsigned ALL = 0x3FFFFu;
    unsigned vmask = ALL;
    if (seg == 0)        vmask &= ~1u;
    if (seg == SEGS - 1) vmask &= ~(1u << 17);
    const unsigned inv = ALL & ~vmask;

    unsigned and1 = eC1 & (vT ? eT1 : ALL) & (vB ? eB1 : ALL);
    unsigned and2 = eC2 & (vT ? eT2 : ALL) & (vB ? eB2 : ALL);
    unsigned or1  = eC1 | (vT ? eT1 : 0u)  | (vB ? eB1 : 0u);
    unsigned or2  = eC2 | (vT ? eT2 : 0u)  | (vB ? eB2 : 0u);
    and1 |= inv;   and2 |= inv;
    or1  &= vmask; or2  &= vmask;

    const unsigned E1 = and1 & (and1 >> 1) & (and1 >> 2);
    const unsigned E2 = and2 & (and2 >> 1) & (and2 >> 2);
    const unsigned D1 = or1  | (or1  >> 1) | (or1  >> 2);
    const unsigned D2 = or2  | (or2  >> 1) | (or2  >> 2);

    // ---- Argmax -> class bitmasks (strict > = first-occurrence tie-break) ----
    const float A[16]  = {qa0.x,qa0.y,qa0.z,qa0.w, qa1.x,qa1.y,qa1.z,qa1.w,
                          qa2.x,qa2.y,qa2.z,qa2.w, qa3.x,qa3.y,qa3.z,qa3.w};
    const float Bv[16] = {qb0.x,qb0.y,qb0.z,qb0.w, qb1.x,qb1.y,qb1.z,qb1.w,
                          qb2.x,qb2.y,qb2.z,qb2.w, qb3.x,qb3.y,qb3.z,qb3.w};
    const float Cv[16] = {qc0.x,qc0.y,qc0.z,qc0.w, qc1.x,qc1.y,qc1.z,qc1.w,
                          qc2.x,qc2.y,qc2.z,qc2.w, qc3.x,qc3.y,qc3.z,qc3.w};
    unsigned P1 = 0u, P2 = 0u;
    #pragma unroll
    for (int j = 0; j < 16; ++j) {
        int   p    = 0;
        float best = A[j];
        if (Bv[j] > best) { best = Bv[j]; p = 1; }
        if (Cv[j] > best) {               p = 2; }
        P1 |= ((p == 1) ? 1u : 0u) << j;
        P2 |= ((p == 2) ? 1u : 0u) << j;
    }

    const unsigned inter = (unsigned)__popc((D2 & P2) | (D1 & ~D2 & P1));
    const unsigned uni   = (unsigned)__popc((E1 | E2 | P1 | P2) & 0xFFFFu);

    // ---- Reduce: wave -> block -> one store per block ----
    unsigned long long packed = (unsigned long long)inter | ((unsigned long long)uni << 32);
    #pragma unroll
    for (int off = 32; off > 0; off >>= 1)
        packed += __shfl_down(packed, off, 64);

    __shared__ unsigned long long wsum[4];
    const int wave = threadIdx.x >> 6;
    if ((threadIdx.x & 63) == 0) wsum[wave] = packed;
    __syncthreads();
    if (threadIdx.x == 0)
        part[(size_t)b * NPART + blockIdx.x] = wsum[0] + wsum[1] + wsum[2] + wsum[3];
}

__global__ void finalize_kernel(const unsigned long long* __restrict__ part,
                                float* __restrict__ out) {
    // 256 threads: 8 threads per batch, each sums 8 of the 64 partials.
    const int t = threadIdx.x;
    const int b = t >> 3;
    const int k = t & 7;
    unsigned long long s = 0ull;
    #pragma unroll
    for (int i = 0; i < 8; ++i)
        s += part[(size_t)b * NPART + k * 8 + i];
    s += __shfl_down(s, 4, 8);
    s += __shfl_down(s, 2, 8);
    s += __shfl_down(s, 1, 8);

    __shared__ float r[NB];
    if (k == 0) {
        const float inter = (float)(unsigned int)(s & 0xFFFFFFFFull);
        const float uni   = (float)(unsigned int)(s >> 32);
        r[b] = inter / uni;
    }
    __syncthreads();
    if (t < 32) {
        float v = r[t];
        #pragma unroll
        for (int off = 16; off > 0; off >>= 1)
            v += __shfl_down(v, off, 32);
        if (t == 0) out[0] = v / (float)NB;
    }
}

extern "C" void kernel_launch(void* const* d_in, const int* in_sizes, int n_in,
                              void* d_out, int out_size, void* d_ws, size_t ws_size,
                              hipStream_t stream) {
    const float* yhat = (const float*)d_in[0];
    const int*   y    = (const int*)d_in[1];
    float*       out  = (float*)d_out;
    unsigned long long* part = (unsigned long long*)d_ws;   // 32*64 u64 = 16 KB

    dim3 grid(GX, NB, 1);
    iou_kernel<<<grid, 256, 0, stream>>>(yhat, y, part);
    finalize_kernel<<<1, 256, 0, stream>>>(part, out);
}